// Round 15
// baseline (275.343 us; speedup 1.0000x reference)
//
#include <hip/hip_runtime.h>
#include <hip/hip_bf16.h>
#include <stdint.h>

// Problem constants (B=2, T=2048, D=2048, H=16, HD=128, ALPHA=1.0)
#define BT    4096
#define DM    2048
#define TSEQ  2048
#define NHEAD 16
#define HD    128
#define QKV_LD 6144
#define ATT_SCALE 0.088388347648318447f   // 128^-0.5
#define WIN   64

typedef __attribute__((ext_vector_type(8))) short short8;
typedef __attribute__((ext_vector_type(4))) float f32x4;

__device__ __forceinline__ uint16_t f2bf(float f) {
  uint32_t u = __float_as_uint(f);
  return (uint16_t)((u + 0x7FFFu + ((u >> 16) & 1u)) >> 16);  // RNE
}

__device__ __forceinline__ void gload_lds16(const void* g, void* l) {
  __builtin_amdgcn_global_load_lds((__attribute__((address_space(1))) void*)g,
                                   (__attribute__((address_space(3))) void*)l,
                                   16, 0, 0);
}

// ---------------- prep: all fp32->bf16 casts + bias concat, one launch ----------------
__global__ __launch_bounds__(256) void prep(const float* __restrict__ x,
                                            const float* __restrict__ qw,
                                            const float* __restrict__ kw,
                                            const float* __restrict__ vw,
                                            const float* __restrict__ ow,
                                            const float* __restrict__ qb,
                                            const float* __restrict__ kb,
                                            const float* __restrict__ vb,
                                            uint16_t* __restrict__ xb,
                                            uint16_t* __restrict__ wqkv,
                                            uint16_t* __restrict__ wo,
                                            float* __restrict__ bcat) {
  const int NX = BT * DM / 4;
  const int NW = DM * DM / 4;
  const int total = NX + 4 * NW;
  int i0 = blockIdx.x * 256 + threadIdx.x;
  for (int idx = i0; idx < total; idx += gridDim.x * 256) {
    const float* src;
    uint16_t* dst;
    int off;
    if (idx < NX)            { src = x;  dst = xb;                          off = idx; }
    else if (idx < NX + NW)  { src = qw; dst = wqkv;                        off = idx - NX; }
    else if (idx < NX + 2*NW){ src = kw; dst = wqkv + (size_t)DM * DM;      off = idx - NX - NW; }
    else if (idx < NX + 3*NW){ src = vw; dst = wqkv + (size_t)2 * DM * DM;  off = idx - NX - 2*NW; }
    else                     { src = ow; dst = wo;                          off = idx - NX - 3*NW; }
    float4 v = ((const float4*)src)[off];
    ushort4 o;
    o.x = f2bf(v.x); o.y = f2bf(v.y); o.z = f2bf(v.z); o.w = f2bf(v.w);
    ((ushort4*)dst)[off] = o;
  }
  if (i0 < 3 * DM) {
    float v = (i0 < DM) ? qb[i0] : (i0 < 2 * DM ? kb[i0 - DM] : vb[i0 - 2 * DM]);
    bcat[i0] = v;
  }
}

// ---------------- 256x384 BK=64 bf16 GEMM, QKV (R10-verified: 93us, 47% MfmaUtil) ----------------
__global__ __launch_bounds__(512, 1) void gemm384(const uint16_t* __restrict__ A,
                                                  const uint16_t* __restrict__ B,
                                                  const float* __restrict__ bias,
                                                  uint16_t* __restrict__ Cout) {
  __shared__ uint16_t sm[81920];   // 160 KiB

  const int tid = threadIdx.x;
  const int l   = tid & 63;
  const int wid = tid >> 6;        // 0..7
  const int wr  = wid >> 2;        // 0..1 (M half)
  const int wc  = wid & 3;         // 0..3 (N quarter, 96 cols each)
  const int ln  = l & 15;
  const int g   = l >> 4;          // 0..3

  // XCD-rect: 32 blocks/XCD, rect 8m x 4n
  const int bid = blockIdx.x;
  const int xcd = bid & 7;
  const int idx = bid >> 3;
  const int m0  = ((xcd >> 2) * 8 + (idx >> 2)) << 8;
  const int n0  = ((xcd & 3) * 4 + (idx & 3)) * 384;

  // stage addressing: unit = 128 rows x 64 K (2 gloads q=0/1, rows +0/+64)
  const int s_r = wid * 8 + (l >> 3);                          // 0..63 (+q*64)
  const int s_c = ((l & 7) ^ ((wid * 4 + (l >> 4)) & 7)) << 3; // pre-swizzled chunk
  const uint16_t* gA = A + (size_t)(m0 + s_r) * DM + s_c;
  const uint16_t* gB = B + (size_t)(n0 + s_r) * DM + s_c;
  const int sdst = wid * 512;

  // read addressing: phys chunk = (kk*4+g) ^ ((ln>>1)&7)  [2-way-free, 0 conflicts]
  const int key  = (ln >> 1) & 7;
  const int pc0  = (g ^ key) << 3;
  const int pc1  = ((4 + g) ^ key) << 3;
  const int aoff = (wr * 128 + ln) * 64;
  const int boff = 16384 + (wc * 96 + ln) * 64;

  f32x4 acc[8][6];
#pragma unroll
  for (int i = 0; i < 8; ++i)
#pragma unroll
    for (int j = 0; j < 6; ++j) acc[i][j] = (f32x4){0.f, 0.f, 0.f, 0.f};

  const int nt = DM >> 6;   // 32

#define STA(T, U)                                                                \
  if ((T) < nt) {                                                                \
    const uint16_t* s_ = gA + (size_t)((U) * 128) * DM + (size_t)(T) * 64;       \
    uint16_t* d_ = sm + ((T) & 1) * 40960 + (U) * 8192 + sdst;                   \
    gload_lds16(s_, d_);                                                         \
    gload_lds16(s_ + (size_t)64 * DM, d_ + 4096);                                \
  }
#define STB(T, U)                                                                \
  if ((T) < nt) {                                                                \
    const uint16_t* s_ = gB + (size_t)((U) * 128) * DM + (size_t)(T) * 64;       \
    uint16_t* d_ = sm + ((T) & 1) * 40960 + 16384 + (U) * 8192 + sdst;           \
    gload_lds16(s_, d_);                                                         \
    gload_lds16(s_ + (size_t)64 * DM, d_ + 4096);                                \
  }
#define FENCE() asm volatile("" ::: "memory")

#define MMH(BUFP, MH, PC)                                                        \
  __builtin_amdgcn_s_setprio(1);                                                 \
  _Pragma("unroll")                                                              \
  for (int mi = 0; mi < 4; ++mi) {                                               \
    short8 af = *(const short8*)((BUFP) + aoff + ((MH) * 64 + mi * 16) * 64 + (PC)); \
    _Pragma("unroll")                                                            \
    for (int nj = 0; nj < 6; ++nj)                                               \
      acc[(MH) * 4 + mi][nj] = __builtin_amdgcn_mfma_f32_16x16x32_bf16(          \
          af, bf[nj], acc[(MH) * 4 + mi][nj], 0, 0, 0);                          \
  }                                                                              \
  __builtin_amdgcn_s_setprio(0);

  STA(0, 0); STA(0, 1);
  STB(0, 0); STB(0, 1); STB(0, 2);
  STB(1, 0); STB(1, 1); STB(1, 2);
  asm volatile("s_waitcnt vmcnt(6)" ::: "memory");
  FENCE(); __builtin_amdgcn_s_barrier(); FENCE();

#pragma unroll 1
  for (int t = 0; t < nt; ++t) {
    const uint16_t* bufp = sm + (size_t)(t & 1) * 40960;
    short8 bf[6];
#pragma unroll
    for (int nj = 0; nj < 6; ++nj)
      bf[nj] = *(const short8*)(bufp + boff + nj * 1024 + pc0);
    STA(t + 1, 0);
    MMH(bufp, 0, pc0);
    STA(t + 1, 1);
    MMH(bufp, 1, pc0);
#pragma unroll
    for (int nj = 0; nj < 6; ++nj)
      bf[nj] = *(const short8*)(bufp + boff + nj * 1024 + pc1);
    MMH(bufp, 0, pc1);
    FENCE(); __builtin_amdgcn_s_barrier(); FENCE();
    STB(t + 2, 0); STB(t + 2, 1); STB(t + 2, 2);
    MMH(bufp, 1, pc1);
    FENCE();
    if (t < nt - 2)       asm volatile("s_waitcnt vmcnt(6)" ::: "memory");
    else if (t == nt - 2) asm volatile("s_waitcnt vmcnt(0)" ::: "memory");
    __builtin_amdgcn_s_barrier(); FENCE();
  }
#undef MMH
#undef STA
#undef STB

  const int g4 = g * 4;
#pragma unroll
  for (int a = 0; a < 8; ++a) {
    size_t row = (size_t)(m0 + wr * 128 + (a >> 2) * 64 + (a & 3) * 16 + g4);
#pragma unroll
    for (int nj = 0; nj < 6; ++nj) {
      int col = n0 + wc * 96 + nj * 16 + ln;
      float bv = bias[col];
#pragma unroll
      for (int r = 0; r < 4; ++r)
        Cout[(row + r) * QKV_LD + col] = f2bf(acc[a][nj][r] + bv);
    }
  }
}

// ---------------- 256x128 O-proj GEMM: A direct-global to regs, B via LDS ----------------
// M=4096, N=2048, K=2048. Grid 16x16 = 256 blocks = 1 balanced round.
// 8 waves (2M x 4N), per-wave C = 128x32 (8x2 frags).
// A fragments read STRAIGHT from global in MFMA layout (row=m+ln, 16B at chunk g):
// 16-row x 64B-line gather, fully line-coalesced (g=0..3 lanes share each line).
// 1-tile register prefetch (an_[8][2]) hides latency under the tile body.
// B double-buffered in 32 KB LDS (R10-verified swizzle pair), 0.125 reads/MFMA.
// vmcnt(2) per tile: queue = leftover B(t+1)(2) + an(16) + B(t+2)(2) -> drain to 2.
__global__ __launch_bounds__(512, 1) void gemmO3(const uint16_t* __restrict__ A,
                                                 const uint16_t* __restrict__ B,
                                                 const float* __restrict__ bias,
                                                 float* __restrict__ Cout) {
  __shared__ uint16_t sm[16384];   // 32 KiB: 2 bufs x B[128][64]

  const int tid = threadIdx.x;
  const int l   = tid & 63;
  const int wid = tid >> 6;        // 0..7
  const int wr  = wid >> 2;        // 0..1 (M half of 128 rows each)
  const int wc  = wid & 3;         // 0..3 (N quarter, 32 cols each)
  const int ln  = l & 15;
  const int g   = l >> 4;          // 0..3

  // XCD-rect: 32 blocks/XCD, rect 8m x 4n (nbm=16, nbn=16)
  const int bid = blockIdx.x;
  const int xcd = bid & 7;
  const int idx = bid >> 3;
  const int m0  = ((xcd >> 2) * 8 + (idx >> 2)) << 8;
  const int n0  = ((xcd & 3) * 4 + (idx & 3)) << 7;

  // A direct-global fragment base: row = m0 + wr*128 + mi*16 + ln, k-chunk g
  const uint16_t* gAf = A + (size_t)(m0 + wr * 128 + ln) * DM + (g << 3);

  // B stage addressing (R10-verified pair): rows n0+s_r (+64), pre-swizzled chunk
  const int s_r = wid * 8 + (l >> 3);
  const int s_c = ((l & 7) ^ ((wid * 4 + (l >> 4)) & 7)) << 3;
  const uint16_t* gB = B + (size_t)(n0 + s_r) * DM + s_c;
  const int sdst = wid * 512;

  // B read addressing: phys chunk = (kk*4+g) ^ ((ln>>1)&7)
  const int key  = (ln >> 1) & 7;
  const int pc0  = (g ^ key) << 3;
  const int pc1  = ((4 + g) ^ key) << 3;
  const int boff = (wc * 32 + ln) * 64;

  f32x4 acc[8][2];
#pragma unroll
  for (int i = 0; i < 8; ++i)
#pragma unroll
    for (int j = 0; j < 2; ++j) acc[i][j] = (f32x4){0.f, 0.f, 0.f, 0.f};

  const int nt = DM >> 6;   // 32

#define STB3(T)                                                                  \
  if ((T) < nt) {                                                                \
    const uint16_t* s_ = gB + (size_t)(T) * 64;                                  \
    uint16_t* d_ = sm + ((T) & 1) * 8192 + sdst;                                 \
    gload_lds16(s_, d_);                                                         \
    gload_lds16(s_ + (size_t)64 * DM, d_ + 4096);                                \
  }
#define FENCE() asm volatile("" ::: "memory")

  short8 a_[8][2], an_[8][2];
  // prologue: A(0) loads FIRST (so vmcnt(2) drains them), then B(0), B(1) stages
#pragma unroll
  for (int mi = 0; mi < 8; ++mi)
#pragma unroll
    for (int kk = 0; kk < 2; ++kk)
      a_[mi][kk] = *(const short8*)(gAf + (size_t)mi * 16 * DM + kk * 32);
  STB3(0);
  STB3(1);
  asm volatile("s_waitcnt vmcnt(2)" ::: "memory");   // A(0)+B(0) landed; B(1) in flight
  FENCE(); __builtin_amdgcn_s_barrier(); FENCE();

#pragma unroll 1
  for (int t = 0; t < nt; ++t) {
    const uint16_t* bufp = sm + (size_t)(t & 1) * 8192;
    // issue next tile's A fragments (register prefetch)
    if (t + 1 < nt) {
#pragma unroll
      for (int mi = 0; mi < 8; ++mi)
#pragma unroll
        for (int kk = 0; kk < 2; ++kk)
          an_[mi][kk] = *(const short8*)(gAf + (size_t)mi * 16 * DM
                                         + (size_t)(t + 1) * 64 + kk * 32);
    }
    short8 bf[2];
    // kk0
#pragma unroll
    for (int nj = 0; nj < 2; ++nj)
      bf[nj] = *(const short8*)(bufp + boff + nj * 1024 + pc0);
    __builtin_amdgcn_s_setprio(1);
#pragma unroll
    for (int mi = 0; mi < 8; ++mi)
#pragma unroll
      for (int nj = 0; nj < 2; ++nj)
        acc[mi][nj] = __builtin_amdgcn_mfma_f32_16x16x32_bf16(
            a_[mi][0], bf[nj], acc[mi][nj], 0, 0, 0);
    __builtin_amdgcn_s_setprio(0);
    // kk1
#pragma unroll
    for (int nj = 0; nj < 2; ++nj)
      bf[nj] = *(const short8*)(bufp + boff + nj * 1024 + pc1);
    __builtin_amdgcn_s_setprio(1);
#pragma unroll
    for (int mi = 0; mi < 8; ++mi)
#pragma unroll
      for (int nj = 0; nj < 2; ++nj)
        acc[mi][nj] = __builtin_amdgcn_mfma_f32_16x16x32_bf16(
            a_[mi][1], bf[nj], acc[mi][nj], 0, 0, 0);
    __builtin_amdgcn_s_setprio(0);
    FENCE(); __builtin_amdgcn_s_barrier(); FENCE();   // all B reads of buf done
    STB3(t + 2);                                      // current buf B region: dead
    FENCE();
    if (t < nt - 2)       asm volatile("s_waitcnt vmcnt(2)" ::: "memory");
    else if (t == nt - 2) asm volatile("s_waitcnt vmcnt(0)" ::: "memory");
    __builtin_amdgcn_s_barrier(); FENCE();
    // commit prefetch
    if (t + 1 < nt) {
#pragma unroll
      for (int mi = 0; mi < 8; ++mi)
#pragma unroll
        for (int kk = 0; kk < 2; ++kk)
          a_[mi][kk] = an_[mi][kk];
    }
  }
#undef STB3
#undef FENCE

  // epilogue: C/D layout col=lane&15, row=(lane>>4)*4+reg [m89]
  const int g4 = g * 4;
#pragma unroll
  for (int mi = 0; mi < 8; ++mi) {
    size_t row = (size_t)(m0 + wr * 128 + mi * 16 + g4);
#pragma unroll
    for (int nj = 0; nj < 2; ++nj) {
      int col = n0 + wc * 32 + nj * 16 + ln;
      float bv = bias[col];
#pragma unroll
      for (int r = 0; r < 4; ++r)
        Cout[(row + r) * DM + col] = acc[mi][nj][r] + bv;
    }
  }
}

// ---------------- MFMA windowed causal attention (unchanged, R2-verified) ----------------
__global__ __launch_bounds__(256) void attn_mfma(const uint16_t* __restrict__ QKV,
                                                 uint16_t* __restrict__ O) {
  __shared__ __align__(16) uint16_t smem[16384 + 17408];
  uint16_t* Qs = smem;
  uint16_t* Vt = smem + 16384;
  uint16_t* Pl = smem;

  const int tid  = threadIdx.x;
  const int lane = tid & 63;
  const int w    = tid >> 6;
  const int g    = lane >> 4;
  const int ln   = lane & 15;

  const int i0 = blockIdx.x * 64;
  const int h  = blockIdx.y;
  const int b  = blockIdx.z;
  const int wb = i0 - 63;
  const size_t hoff  = (size_t)h * HD;
  const size_t bbase = (size_t)b * TSEQ;

#pragma unroll
  for (int it = 0; it < 8; ++it) {
    int s   = it * 256 + tid;
    int row = s >> 4, c = s & 15;
    int j = wb + row;
    if (j >= 0 && j < TSEQ) {
      const uint16_t* gsrc = QKV + (bbase + j) * (size_t)QKV_LD + hoff
                           + (size_t)((c ^ (row & 7)) * 8);
      uint16_t* ldst = Qs + (size_t)(s & ~63) * 8;
      gload_lds16(gsrc, ldst);
    } else {
      uint4 z = {0, 0, 0, 0};
      *(uint4*)(Qs + (size_t)s * 8) = z;
    }
  }

#pragma unroll
  for (int it = 0; it < 4; ++it) {
    int s  = it * 256 + tid;
    int jp = (s & 15) | (it << 4);
    int dc = (s >> 4) & 15;
    int j0 = wb + 2 * jp;
    uint4 va = {0, 0, 0, 0}, vb = {0, 0, 0, 0};
    if (j0 >= 0 && j0 < TSEQ)
      va = *(const uint4*)(QKV + (bbase + j0) * (size_t)QKV_LD + 2 * DM + hoff + dc * 8);
    if (j0 + 1 >= 0 && j0 + 1 < TSEQ)
      vb = *(const uint4*)(QKV + (bbase + j0 + 1) * (size_t)QKV_LD + 2 * DM + hoff + dc * 8);
    const uint16_t* ap = (const uint16_t*)&va;
    const uint16_t* bp = (const uint16_t*)&vb;
#pragma unroll
    for (int t = 0; t < 8; ++t) {
      uint32_t pk = (uint32_t)ap[t] | ((uint32_t)bp[t] << 16);
      *(uint32_t*)(Vt + (size_t)(dc * 8 + t) * 136 + 2 * jp) = pk;
    }
  }

  short8 kreg[4];
  {
    const uint16_t* kp = QKV + (bbase + i0 + w * 16 + ln) * (size_t)QKV_LD
                       + DM + hoff + g * 8;
#pragma unroll
    for (int kc = 0; kc < 4; ++kc) kreg[kc] = *(const short8*)(kp + kc * 32);
  }

  __syncthreads();

  f32x4 acc[8];
#pragma unroll
  for (int nf = 0; nf < 8; ++nf) acc[nf] = (f32x4){0.f, 0.f, 0.f, 0.f};
#pragma unroll
  for (int kc = 0; kc < 4; ++kc) {
#pragma unroll
    for (int nf = 0; nf < 8; ++nf) {
      int row = nf * 16 + ln;
      int chunk = (kc * 4 + g) ^ (row & 7);
      short8 qf = *(const short8*)(Qs + (size_t)row * 128 + chunk * 8);
      acc[nf] = __builtin_amdgcn_mfma_f32_16x16x32_bf16(kreg[kc], qf, acc[nf], 0, 0, 0);
    }
  }

#pragma unroll
  for (int nf = 0; nf < 8; ++nf) {
    int rj = nf * 16 + ln;
    int jg = wb + rj;
#pragma unroll
    for (int r = 0; r < 4; ++r) {
      int il = w * 16 + g * 4 + r;
      int delta = il + 63 - rj;
      float v = acc[nf][r] * ATT_SCALE - (float)delta;
      acc[nf][r] = ((unsigned)delta < 64u && jg >= 0) ? v : -1e30f;
    }
  }

  float inv[4];
#pragma unroll
  for (int r = 0; r < 4; ++r) {
    float mx = acc[0][r];
#pragma unroll
    for (int nf = 1; nf < 8; ++nf) mx = fmaxf(mx, acc[nf][r]);
    mx = fmaxf(mx, __shfl_xor(mx, 1));
    mx = fmaxf(mx, __shfl_xor(mx, 2));
    mx = fmaxf(mx, __shfl_xor(mx, 4));
    mx = fmaxf(mx, __shfl_xor(mx, 8));
    float s = 0.f;
#pragma unroll
    for (int nf = 0; nf < 8; ++nf) {
      float e = __expf(acc[nf][r] - mx);
      acc[nf][r] = e;
      s += e;
    }
    s += __shfl_xor(s, 1);
    s += __shfl_xor(s, 2);
    s += __shfl_xor(s, 4);
    s += __shfl_xor(s, 8);
    inv[r] = 1.0f / s;
  }

  __syncthreads();

#pragma unroll
  for (int nf = 0; nf < 8; ++nf)
#pragma unroll
    for (int r = 0; r < 4; ++r)
      Pl[(size_t)(w * 16 + g * 4 + r) * 136 + nf * 16 + ln] = f2bf(acc[nf][r]);
  asm volatile("s_waitcnt lgkmcnt(0)" ::: "memory");
  __builtin_amdgcn_sched_barrier(0);

  f32x4 o[8];
#pragma unroll
  for (int nf = 0; nf < 8; ++nf) o[nf] = (f32x4){0.f, 0.f, 0.f, 0.f};
#pragma unroll
  for (int kc = 0; kc < 4; ++kc) {
    short8 pa = *(const short8*)(Pl + (size_t)(w * 16 + ln) * 136 + kc * 32 + g * 8);
#pragma unroll
    for (int nf = 0; nf < 8; ++nf) {
      short8 vbf = *(const short8*)(Vt + (size_t)(nf * 16 + ln) * 136 + kc * 32 + g * 8);
      o[nf] = __builtin_amdgcn_mfma_f32_16x16x32_bf16(pa, vbf, o[nf], 0, 0, 0);
    }
  }

  const size_t obase = (bbase + i0 + w * 16) * (size_t)DM + hoff;
#pragma unroll
  for (int nf = 0; nf < 8; ++nf)
#pragma unroll
    for (int r = 0; r < 4; ++r)
      O[obase + (size_t)(g * 4 + r) * DM + nf * 16 + ln] = f2bf(o[nf][r] * inv[r]);
}

// ---------------- launch ----------------
extern "C" void kernel_launch(void* const* d_in, const int* in_sizes, int n_in,
                              void* d_out, int out_size, void* d_ws, size_t ws_size,
                              hipStream_t stream) {
  const float* x   = (const float*)d_in[0];
  const float* q_w = (const float*)d_in[1];
  const float* q_b = (const float*)d_in[2];
  const float* k_w = (const float*)d_in[3];
  const float* k_b = (const float*)d_in[4];
  const float* v_w = (const float*)d_in[5];
  const float* v_b = (const float*)d_in[6];
  const float* o_w = (const float*)d_in[7];
  const float* o_b = (const float*)d_in[8];

  char* ws = (char*)d_ws;
  const size_t XB_BYTES   = (size_t)BT * DM * 2;
  const size_t W_BYTES    = (size_t)DM * DM * 2;
  const size_t WQKV_BYTES = 3 * W_BYTES;

  uint16_t* xb   = (uint16_t*)(ws);
  uint16_t* wqkv = (uint16_t*)(ws + XB_BYTES);
  uint16_t* wo   = (uint16_t*)(ws + XB_BYTES + WQKV_BYTES);
  float*    bcat = (float*)   (ws + XB_BYTES + WQKV_BYTES + W_BYTES);
  uint16_t* QKVb = (uint16_t*)(ws + XB_BYTES + WQKV_BYTES + W_BYTES + 24576);

  prep<<<2048, 256, 0, stream>>>(x, q_w, k_w, v_w, o_w, q_b, k_b, v_b,
                                 xb, wqkv, wo, bcat);

  // fused QKV projection: BM=256 x BN=384: 16x16 = 256 blocks, 1 balanced round
  gemm384<<<256, 512, 0, stream>>>(xb, wqkv, bcat, QKVb);

  dim3 ga(TSEQ / 64, NHEAD, 2);
  attn_mfma<<<ga, 256, 0, stream>>>(QKVb, xb);

  // O projection: A direct-global + B-LDS, 256 blocks, 1 balanced round
  gemmO3<<<256, 512, 0, stream>>>(xb, wo, o_b, (float*)d_out);
}

// Round 16
// 169.858 us; speedup vs baseline: 1.6210x; 1.6210x over previous
//
#include <hip/hip_runtime.h>
#include <hip/hip_bf16.h>
#include <stdint.h>

// Problem constants (B=2, T=2048, D=2048, H=16, HD=128, ALPHA=1.0)
#define BT    4096
#define DM    2048
#define TSEQ  2048
#define NHEAD 16
#define HD    128
#define QKV_LD 6144
#define ATT_SCALE 0.088388347648318447f   // 128^-0.5
#define WIN   64

typedef __attribute__((ext_vector_type(8))) short short8;
typedef __attribute__((ext_vector_type(4))) float f32x4;

__device__ __forceinline__ uint16_t f2bf(float f) {
  uint32_t u = __float_as_uint(f);
  return (uint16_t)((u + 0x7FFFu + ((u >> 16) & 1u)) >> 16);  // RNE
}

__device__ __forceinline__ void gload_lds16(const void* g, void* l) {
  __builtin_amdgcn_global_load_lds((__attribute__((address_space(1))) void*)g,
                                   (__attribute__((address_space(3))) void*)l,
                                   16, 0, 0);
}

// ---------------- prep: all fp32->bf16 casts + bias concat, one launch ----------------
__global__ __launch_bounds__(256) void prep(const float* __restrict__ x,
                                            const float* __restrict__ qw,
                                            const float* __restrict__ kw,
                                            const float* __restrict__ vw,
                                            const float* __restrict__ ow,
                                            const float* __restrict__ qb,
                                            const float* __restrict__ kb,
                                            const float* __restrict__ vb,
                                            uint16_t* __restrict__ xb,
                                            uint16_t* __restrict__ wqkv,
                                            uint16_t* __restrict__ wo,
                                            float* __restrict__ bcat) {
  const int NX = BT * DM / 4;
  const int NW = DM * DM / 4;
  const int total = NX + 4 * NW;
  int i0 = blockIdx.x * 256 + threadIdx.x;
  for (int idx = i0; idx < total; idx += gridDim.x * 256) {
    const float* src;
    uint16_t* dst;
    int off;
    if (idx < NX)            { src = x;  dst = xb;                          off = idx; }
    else if (idx < NX + NW)  { src = qw; dst = wqkv;                        off = idx - NX; }
    else if (idx < NX + 2*NW){ src = kw; dst = wqkv + (size_t)DM * DM;      off = idx - NX - NW; }
    else if (idx < NX + 3*NW){ src = vw; dst = wqkv + (size_t)2 * DM * DM;  off = idx - NX - 2*NW; }
    else                     { src = ow; dst = wo;                          off = idx - NX - 3*NW; }
    float4 v = ((const float4*)src)[off];
    ushort4 o;
    o.x = f2bf(v.x); o.y = f2bf(v.y); o.z = f2bf(v.z); o.w = f2bf(v.w);
    ((ushort4*)dst)[off] = o;
  }
  if (i0 < 3 * DM) {
    float v = (i0 < DM) ? qb[i0] : (i0 < 2 * DM ? kb[i0 - DM] : vb[i0 - 2 * DM]);
    bcat[i0] = v;
  }
}

// ---------------- 256x384 BK=64 bf16 GEMM, QKV (R10 structure, setprio REMOVED) ----------------
// R16 change: no s_setprio around MFMA clusters — suspected LLVM scheduling fence
// serializing ds_read clusters against MFMA clusters (measured R10: t_tile 6970 cyc
// = 3725 MFMA + 2636 LDS, near-perfect serial). Without the fence the compiler can
// hoist phase p+1's independent ds_reads under phase p's MFMAs.
__global__ __launch_bounds__(512, 1) void gemm384(const uint16_t* __restrict__ A,
                                                  const uint16_t* __restrict__ B,
                                                  const float* __restrict__ bias,
                                                  uint16_t* __restrict__ Cout) {
  __shared__ uint16_t sm[81920];   // 160 KiB

  const int tid = threadIdx.x;
  const int l   = tid & 63;
  const int wid = tid >> 6;        // 0..7
  const int wr  = wid >> 2;        // 0..1 (M half)
  const int wc  = wid & 3;         // 0..3 (N quarter, 96 cols each)
  const int ln  = l & 15;
  const int g   = l >> 4;          // 0..3

  // XCD-rect: 32 blocks/XCD, rect 8m x 4n
  const int bid = blockIdx.x;
  const int xcd = bid & 7;
  const int idx = bid >> 3;
  const int m0  = ((xcd >> 2) * 8 + (idx >> 2)) << 8;
  const int n0  = ((xcd & 3) * 4 + (idx & 3)) * 384;

  // stage addressing: unit = 128 rows x 64 K (2 gloads q=0/1, rows +0/+64)
  const int s_r = wid * 8 + (l >> 3);                          // 0..63 (+q*64)
  const int s_c = ((l & 7) ^ ((wid * 4 + (l >> 4)) & 7)) << 3; // pre-swizzled chunk
  const uint16_t* gA = A + (size_t)(m0 + s_r) * DM + s_c;
  const uint16_t* gB = B + (size_t)(n0 + s_r) * DM + s_c;
  const int sdst = wid * 512;

  // read addressing: phys chunk = (kk*4+g) ^ ((ln>>1)&7)  [2-way-free, 0 conflicts]
  const int key  = (ln >> 1) & 7;
  const int pc0  = (g ^ key) << 3;
  const int pc1  = ((4 + g) ^ key) << 3;
  const int aoff = (wr * 128 + ln) * 64;
  const int boff = 16384 + (wc * 96 + ln) * 64;

  f32x4 acc[8][6];
#pragma unroll
  for (int i = 0; i < 8; ++i)
#pragma unroll
    for (int j = 0; j < 6; ++j) acc[i][j] = (f32x4){0.f, 0.f, 0.f, 0.f};

  const int nt = DM >> 6;   // 32

#define STA(T, U)                                                                \
  if ((T) < nt) {                                                                \
    const uint16_t* s_ = gA + (size_t)((U) * 128) * DM + (size_t)(T) * 64;       \
    uint16_t* d_ = sm + ((T) & 1) * 40960 + (U) * 8192 + sdst;                   \
    gload_lds16(s_, d_);                                                         \
    gload_lds16(s_ + (size_t)64 * DM, d_ + 4096);                                \
  }
#define STB(T, U)                                                                \
  if ((T) < nt) {                                                                \
    const uint16_t* s_ = gB + (size_t)((U) * 128) * DM + (size_t)(T) * 64;       \
    uint16_t* d_ = sm + ((T) & 1) * 40960 + 16384 + (U) * 8192 + sdst;           \
    gload_lds16(s_, d_);                                                         \
    gload_lds16(s_ + (size_t)64 * DM, d_ + 4096);                                \
  }
#define FENCE() asm volatile("" ::: "memory")

#define MMH(BUFP, MH, PC)                                                        \
  _Pragma("unroll")                                                              \
  for (int mi = 0; mi < 4; ++mi) {                                               \
    short8 af = *(const short8*)((BUFP) + aoff + ((MH) * 64 + mi * 16) * 64 + (PC)); \
    _Pragma("unroll")                                                            \
    for (int nj = 0; nj < 6; ++nj)                                               \
      acc[(MH) * 4 + mi][nj] = __builtin_amdgcn_mfma_f32_16x16x32_bf16(          \
          af, bf[nj], acc[(MH) * 4 + mi][nj], 0, 0, 0);                          \
  }

  STA(0, 0); STA(0, 1);
  STB(0, 0); STB(0, 1); STB(0, 2);
  STB(1, 0); STB(1, 1); STB(1, 2);
  asm volatile("s_waitcnt vmcnt(6)" ::: "memory");
  FENCE(); __builtin_amdgcn_s_barrier(); FENCE();

#pragma unroll 1
  for (int t = 0; t < nt; ++t) {
    const uint16_t* bufp = sm + (size_t)(t & 1) * 40960;
    short8 bf[6];
#pragma unroll
    for (int nj = 0; nj < 6; ++nj)
      bf[nj] = *(const short8*)(bufp + boff + nj * 1024 + pc0);
    STA(t + 1, 0);
    MMH(bufp, 0, pc0);
    STA(t + 1, 1);
    MMH(bufp, 1, pc0);
#pragma unroll
    for (int nj = 0; nj < 6; ++nj)
      bf[nj] = *(const short8*)(bufp + boff + nj * 1024 + pc1);
    MMH(bufp, 0, pc1);
    FENCE(); __builtin_amdgcn_s_barrier(); FENCE();
    STB(t + 2, 0); STB(t + 2, 1); STB(t + 2, 2);
    MMH(bufp, 1, pc1);
    FENCE();
    if (t < nt - 2)       asm volatile("s_waitcnt vmcnt(6)" ::: "memory");
    else if (t == nt - 2) asm volatile("s_waitcnt vmcnt(0)" ::: "memory");
    __builtin_amdgcn_s_barrier(); FENCE();
  }
#undef MMH
#undef STA
#undef STB

  const int g4 = g * 4;
#pragma unroll
  for (int a = 0; a < 8; ++a) {
    size_t row = (size_t)(m0 + wr * 128 + (a >> 2) * 64 + (a & 3) * 16 + g4);
#pragma unroll
    for (int nj = 0; nj < 6; ++nj) {
      int col = n0 + wc * 96 + nj * 16 + ln;
      float bv = bias[col];
#pragma unroll
      for (int r = 0; r < 4; ++r)
        Cout[(row + r) * QKV_LD + col] = f2bf(acc[a][nj][r] + bv);
    }
  }
}

// ---------------- 256x128 BK=64 bf16 GEMM, O-proj (R13-verified: 39.6us) ----------------
__global__ __launch_bounds__(512, 1) void gemmO(const uint16_t* __restrict__ A,
                                                const uint16_t* __restrict__ B,
                                                const float* __restrict__ bias,
                                                float* __restrict__ Cout) {
  __shared__ uint16_t sm[49152];   // 96 KiB

  const int tid = threadIdx.x;
  const int l   = tid & 63;
  const int wid = tid >> 6;        // 0..7
  const int wr  = wid >> 2;        // 0..1 (M half of 128)
  const int wc  = wid & 3;         // 0..3 (N quarter, 32 cols each)
  const int ln  = l & 15;
  const int g   = l >> 4;          // 0..3

  // XCD-rect: 32 blocks/XCD, rect 8m x 4n (nbm=16, nbn=16)
  const int bid = blockIdx.x;
  const int xcd = bid & 7;
  const int idx = bid >> 3;
  const int m0  = ((xcd >> 2) * 8 + (idx >> 2)) << 8;
  const int n0  = ((xcd & 3) * 4 + (idx & 3)) << 7;

  // stage addressing (R10-verified formula pair)
  const int s_r = wid * 8 + (l >> 3);
  const int s_c = ((l & 7) ^ ((wid * 4 + (l >> 4)) & 7)) << 3;
  const uint16_t* gA = A + (size_t)(m0 + s_r) * DM + s_c;
  const uint16_t* gB = B + (size_t)(n0 + s_r) * DM + s_c;
  const int sdst = wid * 512;

  // read addressing: phys chunk = (kk*4+g) ^ ((ln>>1)&7)
  const int key  = (ln >> 1) & 7;
  const int pc0  = (g ^ key) << 3;
  const int pc1  = ((4 + g) ^ key) << 3;
  const int aoff = (wr * 128 + ln) * 64;
  const int boff = 16384 + (wc * 32 + ln) * 64;

  f32x4 acc[8][2];
#pragma unroll
  for (int i = 0; i < 8; ++i)
#pragma unroll
    for (int j = 0; j < 2; ++j) acc[i][j] = (f32x4){0.f, 0.f, 0.f, 0.f};

  const int nt = DM >> 6;   // 32

#define STA(T, U)                                                                \
  if ((T) < nt) {                                                                \
    const uint16_t* s_ = gA + (size_t)((U) * 128) * DM + (size_t)(T) * 64;       \
    uint16_t* d_ = sm + ((T) & 1) * 24576 + (U) * 8192 + sdst;                   \
    gload_lds16(s_, d_);                                                         \
    gload_lds16(s_ + (size_t)64 * DM, d_ + 4096);                                \
  }
#define STB(T)                                                                   \
  if ((T) < nt) {                                                                \
    const uint16_t* s_ = gB + (size_t)(T) * 64;                                  \
    uint16_t* d_ = sm + ((T) & 1) * 24576 + 16384 + sdst;                        \
    gload_lds16(s_, d_);                                                         \
    gload_lds16(s_ + (size_t)64 * DM, d_ + 4096);                                \
  }
#define FENCE() asm volatile("" ::: "memory")

#define MMH(BUFP, MH, PC)                                                        \
  __builtin_amdgcn_s_setprio(1);                                                 \
  _Pragma("unroll")                                                              \
  for (int mi = 0; mi < 4; ++mi) {                                               \
    short8 af = *(const short8*)((BUFP) + aoff + ((MH) * 64 + mi * 16) * 64 + (PC)); \
    _Pragma("unroll")                                                            \
    for (int nj = 0; nj < 2; ++nj)                                               \
      acc[(MH) * 4 + mi][nj] = __builtin_amdgcn_mfma_f32_16x16x32_bf16(          \
          af, bf[nj], acc[(MH) * 4 + mi][nj], 0, 0, 0);                          \
  }                                                                              \
  __builtin_amdgcn_s_setprio(0);

  // prologue: t0 fully (A x4 + B x2), t1.B x2; wait first 6 -> vmcnt(2)
  STA(0, 0); STA(0, 1);
  STB(0);
  STB(1);
  asm volatile("s_waitcnt vmcnt(2)" ::: "memory");
  FENCE(); __builtin_amdgcn_s_barrier(); FENCE();

#pragma unroll 1
  for (int t = 0; t < nt; ++t) {
    const uint16_t* bufp = sm + (size_t)(t & 1) * 24576;
    short8 bf[2];
    // ph1: B kk0 reads + A-mh0-kk0; stage (t+1).A0
#pragma unroll
    for (int nj = 0; nj < 2; ++nj)
      bf[nj] = *(const short8*)(bufp + boff + nj * 1024 + pc0);
    STA(t + 1, 0);
    MMH(bufp, 0, pc0);
    // ph2: A-mh1-kk0; stage (t+1).A1
    STA(t + 1, 1);
    MMH(bufp, 1, pc0);
    // ph3: B kk1 reads + A-mh0-kk1; barrier (B region fully read)
#pragma unroll
    for (int nj = 0; nj < 2; ++nj)
      bf[nj] = *(const short8*)(bufp + boff + nj * 1024 + pc1);
    MMH(bufp, 0, pc1);
    FENCE(); __builtin_amdgcn_s_barrier(); FENCE();
    // ph4: stage (t+2).B into current buf (dead); A-mh1-kk1; counted vmcnt
    STB(t + 2);
    MMH(bufp, 1, pc1);
    FENCE();
    if (t < nt - 2)       asm volatile("s_waitcnt vmcnt(2)" ::: "memory");
    else if (t == nt - 2) asm volatile("s_waitcnt vmcnt(0)" ::: "memory");
    __builtin_amdgcn_s_barrier(); FENCE();
  }
#undef MMH
#undef STA
#undef STB
#undef FENCE

  // epilogue: C/D layout col=lane&15, row=(lane>>4)*4+reg [m89]
  const int g4 = g * 4;
#pragma unroll
  for (int a = 0; a < 8; ++a) {
    size_t row = (size_t)(m0 + wr * 128 + (a >> 2) * 64 + (a & 3) * 16 + g4);
#pragma unroll
    for (int nj = 0; nj < 2; ++nj) {
      int col = n0 + wc * 32 + nj * 16 + ln;
      float bv = bias[col];
#pragma unroll
      for (int r = 0; r < 4; ++r)
        Cout[(row + r) * DM + col] = acc[a][nj][r] + bv;
    }
  }
}

// ---------------- MFMA windowed causal attention (unchanged, R2-verified) ----------------
__global__ __launch_bounds__(256) void attn_mfma(const uint16_t* __restrict__ QKV,
                                                 uint16_t* __restrict__ O) {
  __shared__ __align__(16) uint16_t smem[16384 + 17408];
  uint16_t* Qs = smem;
  uint16_t* Vt = smem + 16384;
  uint16_t* Pl = smem;

  const int tid  = threadIdx.x;
  const int lane = tid & 63;
  const int w    = tid >> 6;
  const int g    = lane >> 4;
  const int ln   = lane & 15;

  const int i0 = blockIdx.x * 64;
  const int h  = blockIdx.y;
  const int b  = blockIdx.z;
  const int wb = i0 - 63;
  const size_t hoff  = (size_t)h * HD;
  const size_t bbase = (size_t)b * TSEQ;

#pragma unroll
  for (int it = 0; it < 8; ++it) {
    int s   = it * 256 + tid;
    int row = s >> 4, c = s & 15;
    int j = wb + row;
    if (j >= 0 && j < TSEQ) {
      const uint16_t* gsrc = QKV + (bbase + j) * (size_t)QKV_LD + hoff
                           + (size_t)((c ^ (row & 7)) * 8);
      uint16_t* ldst = Qs + (size_t)(s & ~63) * 8;
      gload_lds16(gsrc, ldst);
    } else {
      uint4 z = {0, 0, 0, 0};
      *(uint4*)(Qs + (size_t)s * 8) = z;
    }
  }

#pragma unroll
  for (int it = 0; it < 4; ++it) {
    int s  = it * 256 + tid;
    int jp = (s & 15) | (it << 4);
    int dc = (s >> 4) & 15;
    int j0 = wb + 2 * jp;
    uint4 va = {0, 0, 0, 0}, vb = {0, 0, 0, 0};
    if (j0 >= 0 && j0 < TSEQ)
      va = *(const uint4*)(QKV + (bbase + j0) * (size_t)QKV_LD + 2 * DM + hoff + dc * 8);
    if (j0 + 1 >= 0 && j0 + 1 < TSEQ)
      vb = *(const uint4*)(QKV + (bbase + j0 + 1) * (size_t)QKV_LD + 2 * DM + hoff + dc * 8);
    const uint16_t* ap = (const uint16_t*)&va;
    const uint16_t* bp = (const uint16_t*)&vb;
#pragma unroll
    for (int t = 0; t < 8; ++t) {
      uint32_t pk = (uint32_t)ap[t] | ((uint32_t)bp[t] << 16);
      *(uint32_t*)(Vt + (size_t)(dc * 8 + t) * 136 + 2 * jp) = pk;
    }
  }

  short8 kreg[4];
  {
    const uint16_t* kp = QKV + (bbase + i0 + w * 16 + ln) * (size_t)QKV_LD
                       + DM + hoff + g * 8;
#pragma unroll
    for (int kc = 0; kc < 4; ++kc) kreg[kc] = *(const short8*)(kp + kc * 32);
  }

  __syncthreads();

  f32x4 acc[8];
#pragma unroll
  for (int nf = 0; nf < 8; ++nf) acc[nf] = (f32x4){0.f, 0.f, 0.f, 0.f};
#pragma unroll
  for (int kc = 0; kc < 4; ++kc) {
#pragma unroll
    for (int nf = 0; nf < 8; ++nf) {
      int row = nf * 16 + ln;
      int chunk = (kc * 4 + g) ^ (row & 7);
      short8 qf = *(const short8*)(Qs + (size_t)row * 128 + chunk * 8);
      acc[nf] = __builtin_amdgcn_mfma_f32_16x16x32_bf16(kreg[kc], qf, acc[nf], 0, 0, 0);
    }
  }

#pragma unroll
  for (int nf = 0; nf < 8; ++nf) {
    int rj = nf * 16 + ln;
    int jg = wb + rj;
#pragma unroll
    for (int r = 0; r < 4; ++r) {
      int il = w * 16 + g * 4 + r;
      int delta = il + 63 - rj;
      float v = acc[nf][r] * ATT_SCALE - (float)delta;
      acc[nf][r] = ((unsigned)delta < 64u && jg >= 0) ? v : -1e30f;
    }
  }

  float inv[4];
#pragma unroll
  for (int r = 0; r < 4; ++r) {
    float mx = acc[0][r];
#pragma unroll
    for (int nf = 1; nf < 8; ++nf) mx = fmaxf(mx, acc[nf][r]);
    mx = fmaxf(mx, __shfl_xor(mx, 1));
    mx = fmaxf(mx, __shfl_xor(mx, 2));
    mx = fmaxf(mx, __shfl_xor(mx, 4));
    mx = fmaxf(mx, __shfl_xor(mx, 8));
    float s = 0.f;
#pragma unroll
    for (int nf = 0; nf < 8; ++nf) {
      float e = __expf(acc[nf][r] - mx);
      acc[nf][r] = e;
      s += e;
    }
    s += __shfl_xor(s, 1);
    s += __shfl_xor(s, 2);
    s += __shfl_xor(s, 4);
    s += __shfl_xor(s, 8);
    inv[r] = 1.0f / s;
  }

  __syncthreads();

#pragma unroll
  for (int nf = 0; nf < 8; ++nf)
#pragma unroll
    for (int r = 0; r < 4; ++r)
      Pl[(size_t)(w * 16 + g * 4 + r) * 136 + nf * 16 + ln] = f2bf(acc[nf][r]);
  asm volatile("s_waitcnt lgkmcnt(0)" ::: "memory");
  __builtin_amdgcn_sched_barrier(0);

  f32x4 o[8];
#pragma unroll
  for (int nf = 0; nf < 8; ++nf) o[nf] = (f32x4){0.f, 0.f, 0.f, 0.f};
#pragma unroll
  for (int kc = 0; kc < 4; ++kc) {
    short8 pa = *(const short8*)(Pl + (size_t)(w * 16 + ln) * 136 + kc * 32 + g * 8);
#pragma unroll
    for (int nf = 0; nf < 8; ++nf) {
      short8 vbf = *(const short8*)(Vt + (size_t)(nf * 16 + ln) * 136 + kc * 32 + g * 8);
      o[nf] = __builtin_amdgcn_mfma_f32_16x16x32_bf16(pa, vbf, o[nf], 0, 0, 0);
    }
  }

  const size_t obase = (bbase + i0 + w * 16) * (size_t)DM + hoff;
#pragma unroll
  for (int nf = 0; nf < 8; ++nf)
#pragma unroll
    for (int r = 0; r < 4; ++r)
      O[obase + (size_t)(g * 4 + r) * DM + nf * 16 + ln] = f2bf(o[nf][r] * inv[r]);
}

// ---------------- launch ----------------
extern "C" void kernel_launch(void* const* d_in, const int* in_sizes, int n_in,
                              void* d_out, int out_size, void* d_ws, size_t ws_size,
                              hipStream_t stream) {
  const float* x   = (const float*)d_in[0];
  const float* q_w = (const float*)d_in[1];
  const float* q_b = (const float*)d_in[2];
  const float* k_w = (const float*)d_in[3];
  const float* k_b = (const float*)d_in[4];
  const float* v_w = (const float*)d_in[5];
  const float* v_b = (const float*)d_in[6];
  const float* o_w = (const float*)d_in[7];
  const float* o_b = (const float*)d_in[8];

  char* ws = (char*)d_ws;
  const size_t XB_BYTES   = (size_t)BT * DM * 2;
  const size_t W_BYTES    = (size_t)DM * DM * 2;
  const size_t WQKV_BYTES = 3 * W_BYTES;

  uint16_t* xb   = (uint16_t*)(ws);
  uint16_t* wqkv = (uint16_t*)(ws + XB_BYTES);
  uint16_t* wo   = (uint16_t*)(ws + XB_BYTES + WQKV_BYTES);
  float*    bcat = (float*)   (ws + XB_BYTES + WQKV_BYTES + W_BYTES);
  uint16_t* QKVb = (uint16_t*)(ws + XB_BYTES + WQKV_BYTES + W_BYTES + 24576);

  prep<<<2048, 256, 0, stream>>>(x, q_w, k_w, v_w, o_w, q_b, k_b, v_b,
                                 xb, wqkv, wo, bcat);

  // fused QKV projection: BM=256 x BN=384: 16x16 = 256 blocks, 1 balanced round
  gemm384<<<256, 512, 0, stream>>>(xb, wqkv, bcat, QKVb);

  dim3 ga(TSEQ / 64, NHEAD, 2);
  attn_mfma<<<ga, 256, 0, stream>>>(QKVb, xb);

  // O projection: BM=256 x BN=128: 16x16 = 256 blocks, 1 balanced round
  gemmO<<<256, 512, 0, stream>>>(xb, wo, o_b, (float*)d_out);
}